// Round 14
// baseline (66.596 us; speedup 1.0000x reference)
//
#include <hip/hip_runtime.h>

#define T_WPAD  962048   // reflect-padded waveform length (before zero tail)
#define T_RAW   960000
#define NFRM    1879
#define OUTW    1876
#define MEDLEN  1864
#define WINL    30
#define PADL    14
#define FPB     8        // frames per block
#define NBX     235      // ceil(NFRM / FPB)
#define XLEN    4296     // 7*512 + 705 + pad (float4-divisible)
#define X4LEN   1074

// Lookahead-2 pipelined body, phase p = k mod 6.
// P0..P3 = window slots (X[12s+4k .. +16)); P4 = next data (loaded at k-2);
// P5 = free slot -> receives data for body k+2. AU = A(k); AL = A-slot for
// content k+2. Quad for T on P3 (content 4k+12..16, fully resident).
#define NBODY(P0,P1,P2,P3,P4,P5, AU, AL, K, DO_Q, DO_LD)                        \
    {                                                                           \
        if (DO_LD) { AL = X4[aK + (K) + 2]; P5 = X4[wBase + (K) + 5]; }         \
        const float ew[16] = {P0.x,P0.y,P0.z,P0.w, P1.x,P1.y,P1.z,P1.w,         \
                              P2.x,P2.y,P2.z,P2.w, P3.x,P3.y,P3.z,P3.w};        \
        _Pragma("unroll")                                                       \
        for (int r = 0; r < 12; ++r) {                                          \
            acc[r] = fmaf(AU.x, ew[r + 1], acc[r]);                             \
            acc[r] = fmaf(AU.y, ew[r + 2], acc[r]);                             \
            acc[r] = fmaf(AU.z, ew[r + 3], acc[r]);                             \
            acc[r] = fmaf(AU.w, ew[r + 4], acc[r]);                             \
        }                                                                       \
        if (DO_Q) {                                                             \
            float qq = fmaf(P3.x, P3.x, fmaf(P3.y, P3.y,                        \
                        fmaf(P3.z, P3.z, P3.w * P3.w)));                        \
            Tcur += (double)qq;                                                 \
        }                                                                       \
    }

// ---------------- Kernel 1: NCCF + per-frame lag selection ----------------
// 128 thr = 2 waves; each wave handles FOUR frames (one per 16-lane group).
// g = lane>>4 picks frame-in-wave, s = lane&15 owns lags 12s+1..12s+12.
// Inner loop: period-6 float4 window rotation + period-3 A rotation with
// LOOKAHEAD-2 ds_reads targeted at dead slots (no copies). 2 ds_read_b128 +
// 48 FMA + 1 T-quad per body. Norms in-stream (f64 running quad-sums).
__global__ __launch_bounds__(128) void nccf_kernel(const float* __restrict__ wav,
                                                   int* __restrict__ idxArr) {
    const int bx   = blockIdx.x;
    const int b    = blockIdx.y;
    const int tid  = threadIdx.x;
    const int wave = tid >> 6;           // 0..1
    const int lane = tid & 63;
    const int g    = lane >> 4;          // frame within wave (0..3)
    const int s    = lane & 15;          // lag-group lane (0..15)

    __shared__ __align__(16) float X[XLEN];

    const long a0 = (long)bx * (FPB * 512);
    const float* wrow = wav + (long)b * T_RAW;

    // Stage wp[a0 .. a0+XLEN): vectorized fast path for interior blocks.
    if (bx >= 1 && bx <= NBX - 2) {
        const float4* src = (const float4*)(wrow + (a0 - 1024));
        float4* dst = (float4*)X;
        for (int i = tid; i < X4LEN; i += 128) dst[i] = src[i];
    } else {
        for (int i = tid; i < XLEN; i += 128) {
            float v = 0.0f;
            long t = a0 + i;
            if (t < T_WPAD) {
                long u = t - 1024;
                if (u < 0) u = -u;
                if (u >= T_RAW) u = 2L * (T_RAW - 1) - u;
                v = wrow[u];
            }
            X[i] = v;
        }
    }
    __syncthreads();

    const int F  = wave * 4 + g;         // frame within block (0..7)
    const int gf = bx * FPB + F;         // global frame
    const bool valid = (gf < NFRM);

    float acc[12];
    #pragma unroll
    for (int r = 0; r < 12; ++r) acc[r] = 0.0f;
    float sq[12];                         // X[12s+j]^2, j=0..11
    double Tcur = 0.0;

    float4 Wa, Wb, Wc, Wd, We, Wf, Aa, Ab, Ac;
    const float4* X4 = (const float4*)X;
    const int aK    = F * 128;            // float4 index of Xf[0]
    const int wBase = aK + 3 * s;         // float4 index of Xf[12s]

    // Prologue: window slots 0..4 (contents 0..4), A contents 0..1.
    Wa = X4[wBase + 0]; Wb = X4[wBase + 1]; Wc = X4[wBase + 2];
    Wd = X4[wBase + 3]; We = X4[wBase + 4];
    Aa = X4[aK]; Ab = X4[aK + 1];

    sq[0] = Wa.x * Wa.x; sq[1] = Wa.y * Wa.y; sq[2]  = Wa.z * Wa.z; sq[3]  = Wa.w * Wa.w;
    sq[4] = Wb.x * Wb.x; sq[5] = Wb.y * Wb.y; sq[6]  = Wb.z * Wb.z; sq[7]  = Wb.w * Wb.w;
    sq[8] = Wc.x * Wc.x; sq[9] = Wc.y * Wc.y; sq[10] = Wc.z * Wc.z; sq[11] = Wc.w * Wc.w;
    #pragma unroll
    for (int j = 0; j < 12; ++j) Tcur += (double)sq[j];   // T(12)

    // Main loop: bodies k = 0..119 (20 x 6 phases), all with quad+loads.
    // After body k: T = T(4k+16).
    for (int kg = 0; kg < 20; ++kg) {
        const int k6 = kg * 6;
        NBODY(Wa,Wb,Wc,Wd,We,Wf, Aa, Ac, k6 + 0, 1, 1)
        NBODY(Wb,Wc,Wd,We,Wf,Wa, Ab, Aa, k6 + 1, 1, 1)
        NBODY(Wc,Wd,We,Wf,Wa,Wb, Ac, Ab, k6 + 2, 1, 1)
        NBODY(Wd,We,Wf,Wa,Wb,Wc, Aa, Ac, k6 + 3, 1, 1)
        NBODY(We,Wf,Wa,Wb,Wc,Wd, Ab, Aa, k6 + 4, 1, 1)
        NBODY(Wf,Wa,Wb,Wc,Wd,We, Ac, Ab, k6 + 5, 1, 1)
    }
    // Tail: k = 120..127. Quads through k=124 (-> T(512)); loads through
    // k=125 (window content 130, A content 127); k=126,127 no loads.
    NBODY(Wa,Wb,Wc,Wd,We,Wf, Aa, Ac, 120, 1, 1)
    NBODY(Wb,Wc,Wd,We,Wf,Wa, Ab, Aa, 121, 1, 1)
    NBODY(Wc,Wd,We,Wf,Wa,Wb, Ac, Ab, 122, 1, 1)
    NBODY(Wd,We,Wf,Wa,Wb,Wc, Aa, Ac, 123, 1, 1)
    NBODY(We,Wf,Wa,Wb,Wc,Wd, Ab, Aa, 124, 1, 1)
    NBODY(Wf,Wa,Wb,Wc,Wd,We, Ac, Ab, 125, 0, 1)
    NBODY(Wa,Wb,Wc,Wd,We,Wf, Aa, Ac, 126, 0, 0)
    NBODY(Wb,Wc,Wd,We,Wf,Wa, Ab, Aa, 127, 0, 0)

    const double T512 = Tcur;
    // Trailing elements X[12s+512..524): contents 128,129,130 = Wc, Wd, We.
    float trail[12] = {Wc.x, Wc.y, Wc.z, Wc.w, Wd.x, Wd.y, Wd.z, Wd.w,
                       We.x, We.y, We.z, We.w};

    // Epilogue: per-lag norms. q(r) = T(512+r) - T(r).
    double qv[12];
    {
        double Thi = T512, Tlo = 0.0;
        #pragma unroll
        for (int r = 1; r <= 12; ++r) {
            float eh = trail[r - 1];          // X[12s+512+(r-1)]
            Thi += (double)(eh * eh);
            Tlo += (double)sq[r - 1];
            qv[r - 1] = Thi - Tlo;
        }
    }
    double s1d = __shfl(T512, 0, 16);         // frame sumsq P[512] (s=0 lane)

    // Per-lane selection over its 12 lags (fp32, np-like first-max ties).
    float bestv = -1e30f, halfv = -1e30f;
    int bestk = 1 << 30, halfk = 1 << 30;
    {
        float s1 = 1e-9f + sqrtf((float)s1d);
        float s1n = s1 * s1;
        #pragma unroll
        for (int r = 1; r <= 12; ++r) {
            int lag  = 12 * s + r;
            int kidx = lag - 1;               // nccf lag index 0..191
            if (kidx <= 188) {
                float s2 = 1e-9f + sqrtf((float)qv[r - 1]);
                float v  = acc[r - 1] / s1n / (s2 * s2);
                if (kidx >= 5) {
                    if (v > bestv) { bestv = v; bestk = kidx; }
                    if (kidx <= 93 && v > halfv) { halfv = v; halfk = kidx; }
                }
            }
        }
    }

    // 16-lane (max, first-argmax) reduction for both slices.
    #pragma unroll
    for (int off = 8; off >= 1; off >>= 1) {
        float ov = __shfl_xor(bestv, off, 16); int ok = __shfl_xor(bestk, off, 16);
        if (ov > bestv || (ov == bestv && ok < bestk)) { bestv = ov; bestk = ok; }
        float hv = __shfl_xor(halfv, off, 16); int hk = __shfl_xor(halfk, off, 16);
        if (hv > halfv || (hv == halfv && hk < halfk)) { halfv = hv; halfk = hk; }
    }

    if (valid && s == 0) {
        bool m = (halfv > 0.99f * bestv);
        int sel = m ? halfk : bestk;
        idxArr[b * NFRM + gf] = sel + 1;      // = chosen lag
    }
}

// ---------------- Kernel 2: 30-wide median filter + pitch ----------------
__global__ __launch_bounds__(256) void med_kernel(const int* __restrict__ idxArr,
                                                  float* __restrict__ out) {
    int gid = blockIdx.x * 256 + threadIdx.x;
    if (gid >= 8 * OUTW) return;
    int b = gid / OUTW;
    int i = gid - b * OUTW;
    float o = 0.0f;
    if (i < MEDLEN) {
        const int* row = idxArr + b * NFRM;
        int vals[WINL];
        #pragma unroll
        for (int m = 0; m < WINL; ++m) {
            int sIdx = i + m - PADL;          // left pad = repeat idx[0]
            vals[m] = row[sIdx < 0 ? 0 : sIdx];
        }
        int med = vals[0];
        #pragma unroll
        for (int c = 0; c < WINL; ++c) {
            int cl = 0, ce = 0;
            #pragma unroll
            for (int m = 0; m < WINL; ++m) {
                cl += (vals[m] <  vals[c]) ? 1 : 0;
                ce += (vals[m] == vals[c]) ? 1 : 0;
            }
            if (cl <= 14 && 14 < cl + ce) med = vals[c];   // rank-14 = sorted[14]
        }
        o = 16000.0f / (1e-9f + (float)med);
    }
    out[gid] = o;
}

extern "C" void kernel_launch(void* const* d_in, const int* in_sizes, int n_in,
                              void* d_out, int out_size, void* d_ws, size_t ws_size,
                              hipStream_t stream) {
    const float* wav = (const float*)d_in[0];
    float* out = (float*)d_out;
    int* idxArr = (int*)d_ws;                 // 8*1879 ints = 60128 B

    dim3 gB(NBX, 8);                          // 235 x 8 blocks, 8 frames each
    hipLaunchKernelGGL(nccf_kernel, gB, dim3(128), 0, stream, wav, idxArr);

    int total = 8 * OUTW;
    hipLaunchKernelGGL(med_kernel, dim3((total + 255) / 256), dim3(256), 0, stream,
                       idxArr, out);
}